// Round 1
// baseline (530.798 us; speedup 1.0000x reference)
//
#include <hip/hip_runtime.h>
#include <stdint.h>

// WindowAttention (focal) on gfx950.
// Pipeline: k_setup -> k_qkv_main -> k_qkv_pool -> k_attn -> k_proj
// R4: k_qkv_main/k_proj restructured: M=128/block, double-buffered LDS weight
// staging, weights pre-swizzled into MFMA fragment order (w1s/w2s).
// R5: k_attn bias table repacked to bf16 fragment order bias_bf[h][nt][l16][row]
// -> one 8B load per nt per thread (was 60 scalar fp32 loads); per-head slice
// 45KB->30KB now fits L1 and is reused by 2048 blocks/head.

#define DIM 192
#define HEADS 6
#define HD 32
#define WA 49
#define NKEY 230
#define SSTR 272                 // S/P row stride in shorts (R1-proven)
#define VSTR 264                 // vT row stride in shorts
#define SCALE_F 0.17677669529663687f

typedef __attribute__((ext_vector_type(8))) short bf16x8;  // 8 bf16 in 4 VGPRs
typedef __attribute__((ext_vector_type(4))) float f32x4;

__device__ __forceinline__ short f2bf(float f) {
  union { float f; uint32_t u; } v; v.f = f;
  uint32_t u = v.u;
  return (short)((u + 0x7FFFu + ((u >> 16) & 1u)) >> 16);  // RNE
}

__device__ __forceinline__ float bf2f(short s) {
  union { uint32_t u; float f; } v;
  v.u = ((uint32_t)(uint16_t)s) << 16;
  return v.f;
}

// ---------------- setup: bf16 weights (plain + fragment-swizzled), tables ----
// Swizzle: tile t = 32 rows; frag (ntl,ks,quad,l16) holds w[t*32+ntl*16+l16]
// [ks*32+quad*8 .. +8). Tile = 6144 shorts.
// bias_bf layout: [h][nt][l16][row64] bf16; value for (row, key=nt*16+l16),
// zero when row>=49 or key>=230.
__global__ __launch_bounds__(256) void k_setup(
    const float* __restrict__ qkv_w, const float* __restrict__ proj_w,
    const float* __restrict__ rpb_table, const float* __restrict__ rpb_nb,
    const float* __restrict__ rpb_win,
    short* __restrict__ w1, short* __restrict__ w1s, short* __restrict__ w2s,
    int2* __restrict__ ring, short* __restrict__ bias_bf) {
  const int tid = blockIdx.x * blockDim.x + threadIdx.x;
  const int nth = gridDim.x * blockDim.x;
  for (int i = tid; i < 576 * DIM; i += nth) {
    float fv = qkv_w[i];
    w1[i] = f2bf(fv);
    int r = i / DIM, c = i % DIM;
    int t = r >> 5, ntl = (r >> 4) & 1, lr = r & 15;
    int ks = c >> 5, quad = (c >> 3) & 3, e = c & 7;
    w1s[t * 6144 + (((ntl * 6 + ks) * 4 + quad) * 16 + lr) * 8 + e] = f2bf(fv);
  }
  for (int i = tid; i < DIM * DIM; i += nth) {
    int r = i / DIM, c = i % DIM;
    int t = r >> 5, ntl = (r >> 4) & 1, lr = r & 15;
    int ks = c >> 5, quad = (c >> 3) & 3, e = c & 7;
    w2s[t * 6144 + (((ntl * 6 + ks) * 4 + quad) * 16 + lr) * 8 + e] = f2bf(proj_w[i]);
  }
  for (int e = tid; e < 132; e += nth) {
    int cnt = 0, fdr = 0, fdc = 0;
    for (int idx = 0; idx < 196; ++idx) {
      int s = idx / 49, rc = idx % 49, r = rc / 7, c = rc % 7;
      bool valid;
      if (s == 0)      valid = (r >= 4) || (c >= 4);
      else if (s == 1) valid = (r >= 4) || (c < 3);
      else if (s == 2) valid = (r < 3)  || (c >= 4);
      else             valid = (r < 3)  || (c < 3);
      if (valid) {
        if (cnt == e) { fdr = r + ((s < 2) ? 3 : -3); fdc = c + (((s & 1) == 0) ? 3 : -3); }
        ++cnt;
      }
    }
    ring[e] = make_int2(fdr, fdc);
  }
  // bias_bf: HEADS * 15 * 16 * 64 entries
  for (int i = tid; i < HEADS * 15 * 1024; i += nth) {
    int row = i & 63, l16 = (i >> 6) & 15;
    int rem = i >> 10, nt = rem % 15, h = rem / 15;
    int kk = nt * 16 + l16;
    float bv = 0.f;
    if (row < WA && kk < NKEY) {
      if (kk < 49) {
        int ar = row / 7, ac = row % 7, br = kk / 7, bc = kk % 7;
        bv = rpb_table[((ar - br + 6) * 13 + (ac - bc + 6)) * HEADS + h];
      } else if (kk < 181) {
        bv = rpb_nb[((size_t)h * WA + row) * 132 + (kk - 49)];
      } else {
        int p = kk - 181;
        int ar = row / 7, ac = row % 7, br = p / 7, bc = p % 7;
        bv = rpb_win[h * 169 + (ar - br + 6) * 13 + (ac - bc + 6)];
      }
    }
    bias_bf[i] = f2bf(bv);
  }
}

// ---------------- QKV on fine map: M=100352, N=576, K=192 ----------------
// 128 rows/block, double-buffered LDS weight tiles (32 cols x 192 ch).
__global__ __launch_bounds__(256, 4) void k_qkv_main(
    const float* __restrict__ x, const short* __restrict__ w1s, const float* __restrict__ qkv_b,
    short* __restrict__ qw, short* __restrict__ kn, short* __restrict__ vn) {
  __shared__ __align__(16) short wbuf[2][6144];
  const int tid = threadIdx.x;
  const int wave = tid >> 6, lane = tid & 63, quad = lane >> 4, l16 = lane & 15;
  const int mbase = blockIdx.x * 128;

  bf16x8 afr[2][6];
#pragma unroll
  for (int mt = 0; mt < 2; ++mt) {
    const float* xrow = x + (size_t)(mbase + wave * 32 + mt * 16 + l16) * DIM + quad * 8;
#pragma unroll
    for (int ks = 0; ks < 6; ++ks) {
      float4 f0 = *(const float4*)(xrow + ks * 32);
      float4 f1 = *(const float4*)(xrow + ks * 32 + 4);
      bf16x8 a;
      a[0] = f2bf(f0.x); a[1] = f2bf(f0.y); a[2] = f2bf(f0.z); a[3] = f2bf(f0.w);
      a[4] = f2bf(f1.x); a[5] = f2bf(f1.y); a[6] = f2bf(f1.z); a[7] = f2bf(f1.w);
      afr[mt][ks] = a;
    }
  }
  uint32_t q_base[2][4], kv_base[2][4];
#pragma unroll
  for (int mt = 0; mt < 2; ++mt)
#pragma unroll
    for (int rg = 0; rg < 4; ++rg) {
      int m = mbase + wave * 32 + mt * 16 + quad * 4 + rg;
      int bb = m / 12544, rem = m % 12544;
      int i = rem / 112, j = rem % 112;
      int wr = i / 7, rr = i % 7, wc = j / 7, cc = j % 7;
      int winid = (bb * 16 + wr) * 16 + wc;
      q_base[mt][rg]  = ((uint32_t)winid * WA + (rr * 7 + cc)) * DIM;
      kv_base[mt][rg] = (uint32_t)m * DIM;
    }

  int4 st[3];
  {
    const int4* src = (const int4*)w1s + tid;
#pragma unroll
    for (int it = 0; it < 3; ++it) st[it] = src[it * 256];
  }
  for (int t = 0; t < 18; ++t) {
    short* buf = wbuf[t & 1];
#pragma unroll
    for (int it = 0; it < 3; ++it) ((int4*)buf)[tid + it * 256] = st[it];
    __syncthreads();
    if (t < 17) {
      const int4* src = (const int4*)(w1s + (t + 1) * 6144) + tid;
#pragma unroll
      for (int it = 0; it < 3; ++it) st[it] = src[it * 256];
    }
#pragma unroll
    for (int ntl = 0; ntl < 2; ++ntl) {
      const int n = t * 32 + ntl * 16 + l16;
      bf16x8 bfr[6];
#pragma unroll
      for (int ks = 0; ks < 6; ++ks)
        bfr[ks] = *(const bf16x8*)&buf[(((ntl * 6 + ks) * 4 + quad) * 16 + l16) * 8];
      const float bias = qkv_b[n];
#pragma unroll
      for (int mt = 0; mt < 2; ++mt) {
        f32x4 acc = {0.f, 0.f, 0.f, 0.f};
#pragma unroll
        for (int ks = 0; ks < 6; ++ks)
          acc = __builtin_amdgcn_mfma_f32_16x16x32_bf16(afr[mt][ks], bfr[ks], acc, 0, 0, 0);
#pragma unroll
        for (int rg = 0; rg < 4; ++rg) {
          float vo = acc[rg] + bias;
          if (t < 6)       qw[q_base[mt][rg] + n]           = f2bf(vo * SCALE_F);
          else if (t < 12) kn[kv_base[mt][rg] + (n - 192)]  = f2bf(vo);
          else             vn[kv_base[mt][rg] + (n - 384)]  = f2bf(vo);
        }
      }
    }
  }
}

// ---------------- QKV on pooled map: M=2048, only k,v (R3-proven) ----------
__global__ __launch_bounds__(256) void k_qkv_pool(
    const float* __restrict__ xp, const short* __restrict__ w1, const float* __restrict__ qkv_b,
    short* __restrict__ kp, short* __restrict__ vp) {
  const int tid = threadIdx.x;
  const int wave = tid >> 6, lane = tid & 63, quad = lane >> 4, l16 = lane & 15;
  const int mbase = (blockIdx.x * 4 + wave) * 16;

  bf16x8 afr[6];
  {
    const float* xrow = xp + (size_t)(mbase + l16) * DIM + quad * 8;
#pragma unroll
    for (int ks = 0; ks < 6; ++ks) {
      float4 f0 = *(const float4*)(xrow + ks * 32);
      float4 f1 = *(const float4*)(xrow + ks * 32 + 4);
      bf16x8 a;
      a[0] = f2bf(f0.x); a[1] = f2bf(f0.y); a[2] = f2bf(f0.z); a[3] = f2bf(f0.w);
      a[4] = f2bf(f1.x); a[5] = f2bf(f1.y); a[6] = f2bf(f1.z); a[7] = f2bf(f1.w);
      afr[ks] = a;
    }
  }
  for (int nt = 12; nt < 36; ++nt) {
    const int n = nt * 16 + l16;
    const short* wrow = w1 + (size_t)n * DIM + quad * 8;
    f32x4 acc = {0.f, 0.f, 0.f, 0.f};
#pragma unroll
    for (int ks = 0; ks < 6; ++ks)
      acc = __builtin_amdgcn_mfma_f32_16x16x32_bf16(afr[ks], *(const bf16x8*)(wrow + ks * 32), acc, 0, 0, 0);
    const float bias = qkv_b[n];
#pragma unroll
    for (int rg = 0; rg < 4; ++rg) {
      int m = mbase + quad * 4 + rg;
      float vo = acc[rg] + bias;
      if (nt < 24) kp[(size_t)m * DIM + (n - 192)] = f2bf(vo);
      else         vp[(size_t)m * DIM + (n - 384)] = f2bf(vo);
    }
  }
}

// ---------------- attention v3 + bf16 fragment-order bias (R5) ----------------
__global__ __launch_bounds__(256, 3) void k_attn(
    const short* __restrict__ qw, const short* __restrict__ kn, const short* __restrict__ vn,
    const short* __restrict__ kpool, const short* __restrict__ vpool,
    const short* __restrict__ bias_bf, const int2* __restrict__ ring,
    short* __restrict__ ao) {
  __shared__ __align__(16) char smem[51968];
  short* vT_l  = (short*)smem;
  short* k_l   = (short*)(smem + 16896);
  short* q_l   = (short*)(smem + 16896 + 19200);
  short* S_l   = (short*)(smem + 16896);          // overlay (phase >= 3)
  float* pmask = (float*)(smem + 51712);

  const int tid = threadIdx.x;
  const int bid = blockIdx.x;
  const int win = bid / HEADS;
  const int h   = bid - win * HEADS;
  const int b   = win >> 8;
  const int wr  = (win >> 4) & 15;
  const int wc  = win & 15;
  const int wave = tid >> 6, lane = tid & 63, quad = lane >> 4, l16 = lane & 15;

  {
    int* kli = (int*)k_l;
    for (int i = tid; i < 200; i += 256) kli[4600 + i] = 0;
    int* qli = (int*)q_l;
    for (int i = tid; i < 300; i += 256) qli[980 + i] = 0;
    if (tid < 128) {
      int ch = tid >> 2, j = tid & 3;
      *(int4*)&vT_l[ch * VSTR + 224 + j * 8] = make_int4(0, 0, 0, 0);
    }
    if (tid < 64) {
      float pm = 0.f;
      if (tid < WA) {
        int pi = wr - 3 + tid / 7, pj = wc - 3 + tid % 7;
        if (pi < 0 || pi >= 16 || pj < 0 || pj >= 16) pm = -100.f;
      }
      pmask[tid] = pm;
    }
  }
  __syncthreads();

  if (tid < 196) {
    int r = tid >> 2, part = tid & 3;
    *(int4*)&q_l[r * 40 + part * 8] =
        *(const int4*)(qw + ((size_t)win * WA + r) * DIM + h * HD + part * 8);
  }
  {
    const int part = tid & 3;
    const int choff = h * HD + part * 8;
    for (int it = 0; it < 4; ++it) {
      int kk = it * 64 + (tid >> 2);
      if (kk < NKEY) {
        int4 kvv = make_int4(0, 0, 0, 0), vvv = make_int4(0, 0, 0, 0);
        const short* ksrc = nullptr; const short* vsrc = nullptr;
        if (kk < WA) {
          int i = wr * 7 + kk / 7, j = wc * 7 + kk % 7;
          size_t t = ((size_t)(b * 112 + i)) * 112 + j;
          ksrc = kn + t * DIM + choff; vsrc = vn + t * DIM + choff;
        } else if (kk < 181) {
          int2 rr = ring[kk - 49];
          int i = wr * 7 + rr.x; if (i < 0) i += 112; if (i >= 112) i -= 112;
          int j = wc * 7 + rr.y; if (j < 0) j += 112; if (j >= 112) j -= 112;
          size_t t = ((size_t)(b * 112 + i)) * 112 + j;
          ksrc = kn + t * DIM + choff; vsrc = vn + t * DIM + choff;
        } else {
          int p = kk - 181;
          int i = wr - 3 + p / 7, j = wc - 3 + p % 7;
          if (i >= 0 && i < 16 && j >= 0 && j < 16) {
            size_t t = ((size_t)(b * 16 + i)) * 16 + j;
            ksrc = kpool + t * DIM + choff; vsrc = vpool + t * DIM + choff;
          }
        }
        if (ksrc) { kvv = *(const int4*)ksrc; vvv = *(const int4*)vsrc; }
        *(int4*)&k_l[kk * 40 + part * 8] = kvv;
        const short* vs = (const short*)&vvv;
#pragma unroll
        for (int e = 0; e < 8; ++e) vT_l[(part * 8 + e) * VSTR + kk] = vs[e];
      }
    }
  }
  __syncthreads();

  f32x4 acc[15];
  {
    bf16x8 qfr = *(const bf16x8*)&q_l[(wave * 16 + l16) * 40 + quad * 8];
#pragma unroll
    for (int nt = 0; nt < 15; ++nt) {
      bf16x8 kfr = *(const bf16x8*)&k_l[(nt * 16 + l16) * 40 + quad * 8];
      f32x4 z = {0.f, 0.f, 0.f, 0.f};
      acc[nt] = __builtin_amdgcn_mfma_f32_16x16x32_bf16(qfr, kfr, z, 0, 0, 0);
    }
  }
  const int rowb = wave * 16 + quad * 4;
  // bias: bf16 fragment order [h][nt][l16][row64]; 8B load per nt covers rg 0..3
  {
    const short* bb = bias_bf + ((size_t)(h * 15) * 16 + l16) * 64 + rowb;
#pragma unroll
    for (int nt = 0; nt < 15; ++nt) {
      const int key = nt * 16 + l16;
      const bool kval = key < NKEY;
      const float pm = (key >= 181 && kval) ? pmask[key - 181] : 0.f;
      int2 braw = *(const int2*)(bb + nt * 1024);
      const short* bs = (const short*)&braw;
#pragma unroll
      for (int rg = 0; rg < 4; ++rg) {
        acc[nt][rg] = kval ? (acc[nt][rg] + bf2f(bs[rg]) + pm) : -1e30f;
      }
    }
  }
  float m4[4] = {-1e30f, -1e30f, -1e30f, -1e30f};
#pragma unroll
  for (int nt = 0; nt < 15; ++nt)
#pragma unroll
    for (int rg = 0; rg < 4; ++rg) m4[rg] = fmaxf(m4[rg], acc[nt][rg]);
#pragma unroll
  for (int msk = 1; msk <= 8; msk <<= 1)
#pragma unroll
    for (int rg = 0; rg < 4; ++rg) m4[rg] = fmaxf(m4[rg], __shfl_xor(m4[rg], msk));
  float s4[4] = {0.f, 0.f, 0.f, 0.f};
#pragma unroll
  for (int nt = 0; nt < 15; ++nt)
#pragma unroll
    for (int rg = 0; rg < 4; ++rg) {
      float e = __expf(acc[nt][rg] - m4[rg]);
      acc[nt][rg] = e; s4[rg] += e;
    }
#pragma unroll
  for (int msk = 1; msk <= 8; msk <<= 1)
#pragma unroll
    for (int rg = 0; rg < 4; ++rg) s4[rg] += __shfl_xor(s4[rg], msk);
  float inv4[4];
#pragma unroll
  for (int rg = 0; rg < 4; ++rg) inv4[rg] = 1.f / s4[rg];
#pragma unroll
  for (int nt = 0; nt < 15; ++nt)
#pragma unroll
    for (int rg = 0; rg < 4; ++rg) acc[nt][rg] *= inv4[rg];

  __syncthreads();

#pragma unroll
  for (int nt = 0; nt < 15; ++nt)
#pragma unroll
    for (int rg = 0; rg < 4; ++rg)
      S_l[(rowb + rg) * SSTR + nt * 16 + l16] = f2bf(acc[nt][rg]);
  {
    int rr = tid >> 2, c0 = 240 + (tid & 3) * 4;
    *(int2*)&S_l[rr * SSTR + c0] = make_int2(0, 0);
  }
  __syncthreads();

#pragma unroll
  for (int nt2 = 0; nt2 < 2; ++nt2) {
    f32x4 acc2 = {0.f, 0.f, 0.f, 0.f};
#pragma unroll
    for (int k0 = 0; k0 < 8; ++k0) {
      bf16x8 pfr = *(const bf16x8*)&S_l[(wave * 16 + l16) * SSTR + k0 * 32 + quad * 8];
      bf16x8 vfr = *(const bf16x8*)&vT_l[(nt2 * 16 + l16) * VSTR + k0 * 32 + quad * 8];
      acc2 = __builtin_amdgcn_mfma_f32_16x16x32_bf16(pfr, vfr, acc2, 0, 0, 0);
    }
#pragma unroll
    for (int rg = 0; rg < 4; ++rg) {
      int row = rowb + rg;
      if (row < WA)
        ao[((size_t)win * WA + row) * DIM + h * HD + nt2 * 16 + l16] = f2bf(acc2[rg]);
    }
  }
}

// ---------------- proj: M=100352, N=192, K=192, fp32 out ----------------
__global__ __launch_bounds__(256, 4) void k_proj(
    const short* __restrict__ ao, const short* __restrict__ w2s, const float* __restrict__ pb,
    float* __restrict__ out) {
  __shared__ __align__(16) short wbuf[2][6144];
  const int tid = threadIdx.x;
  const int wave = tid >> 6, lane = tid & 63, quad = lane >> 4, l16 = lane & 15;
  const int mbase = blockIdx.x * 128;

  bf16x8 afr[2][6];
#pragma unroll
  for (int mt = 0; mt < 2; ++mt) {
    const short* arow = ao + (size_t)(mbase + wave * 32 + mt * 16 + l16) * DIM + quad * 8;
#pragma unroll
    for (int ks = 0; ks < 6; ++ks) afr[mt][ks] = *(const bf16x8*)(arow + ks * 32);
  }
  int4 st[3];
  {
    const int4* src = (const int4*)w2s + tid;
#pragma unroll
    for (int it = 0; it < 3; ++it) st[it] = src[it * 256];
  }
  for (int t = 0; t < 6; ++t) {
    short* buf = wbuf[t & 1];
#pragma unroll
    for (int it = 0; it < 3; ++it) ((int4*)buf)[tid + it * 256] = st[it];
    __syncthreads();
    if (t < 5) {
      const int4* src = (const int4*)(w2s + (t + 1) * 6144) + tid;
#pragma unroll
      for (int it = 0; it < 3; ++it) st[it] = src[it * 256];
    }
#pragma unroll
    for (int ntl = 0; ntl < 2; ++ntl) {
      const int n = t * 32 + ntl * 16 + l16;
      bf16x8 bfr[6];
#pragma unroll
      for (int ks = 0; ks < 6; ++ks)
        bfr[ks] = *(const bf16x8*)&buf[(((ntl * 6 + ks) * 4 + quad) * 16 + l16) * 8];
      const float bias = pb[n];
#pragma unroll
      for (int mt = 0; mt < 2; ++mt) {
        f32x4 acc = {0.f, 0.f, 0.f, 0.f};
#pragma unroll
        for (int ks = 0; ks < 6; ++ks)
          acc = __builtin_amdgcn_mfma_f32_16x16x32_bf16(afr[mt][ks], bfr[ks], acc, 0, 0, 0);
#pragma unroll
        for (int rg = 0; rg < 4; ++rg)
          out[(size_t)(mbase + wave * 32 + mt * 16 + quad * 4 + rg) * DIM + n] = acc[rg] + bias;
      }
    }
  }
}

extern "C" void kernel_launch(void* const* d_in, const int* in_sizes, int n_in,
                              void* d_out, int out_size, void* d_ws, size_t ws_size,
                              hipStream_t stream) {
  (void)in_sizes; (void)n_in; (void)out_size; (void)ws_size;
  const float* x         = (const float*)d_in[0];
  const float* xp        = (const float*)d_in[1];
  const float* qkv_w     = (const float*)d_in[2];
  const float* qkv_b     = (const float*)d_in[3];
  const float* proj_w    = (const float*)d_in[4];
  const float* proj_b    = (const float*)d_in[5];
  const float* rpb_table = (const float*)d_in[6];
  const float* rpb_nb    = (const float*)d_in[7];
  const float* rpb_win   = (const float*)d_in[8];

  char* ws = (char*)d_ws;
  size_t off = 0;
  auto alloc = [&](size_t bytes) -> void* {
    void* p = ws + off; off = (off + bytes + 255) & ~(size_t)255; return p;
  };
  short* w1       = (short*)alloc((size_t)576 * DIM * 2);
  short* w1s      = (short*)alloc((size_t)576 * DIM * 2);
  short* w2s      = (short*)alloc((size_t)DIM * DIM * 2);
  int2*  ring     = (int2*) alloc(132 * sizeof(int2));
  short* bias_bf  = (short*)alloc((size_t)HEADS * 15 * 1024 * 2);
  short* qw       = (short*)alloc((size_t)2048 * WA * DIM * 2);
  short* kn       = (short*)alloc((size_t)8 * 112 * 112 * DIM * 2);
  short* vn       = (short*)alloc((size_t)8 * 112 * 112 * DIM * 2);
  short* kp       = (short*)alloc((size_t)2048 * DIM * 2);
  short* vp       = (short*)alloc((size_t)2048 * DIM * 2);
  short* ao       = (short*)alloc((size_t)2048 * WA * DIM * 2);

  k_setup<<<dim3(64), dim3(256), 0, stream>>>(qkv_w, proj_w, rpb_table, rpb_nb, rpb_win,
                                              w1, w1s, w2s, ring, bias_bf);
  k_qkv_main<<<dim3(784), dim3(256), 0, stream>>>(x, w1s, qkv_b, qw, kn, vn);
  k_qkv_pool<<<dim3(32), dim3(256), 0, stream>>>(xp, w1, qkv_b, kp, vp);
  k_attn<<<dim3(12288), dim3(256), 0, stream>>>(qw, kn, vn, kp, vp, bias_bf, ring, ao);
  k_proj<<<dim3(784), dim3(256), 0, stream>>>(ao, w2s, proj_b, (float*)d_out);
}

// Round 3
// 511.125 us; speedup vs baseline: 1.0385x; 1.0385x over previous
//
#include <hip/hip_runtime.h>
#include <stdint.h>

// WindowAttention (focal) on gfx950.
// Pipeline: k_setup -> k_qkv_main -> k_qkv_pool -> k_attn -> k_proj
// R4: k_qkv_main/k_proj: M=128/block, double-buffered LDS weight staging,
//     weights pre-swizzled into MFMA fragment order (w1s/w2s).
// R5: bias table repacked to bf16 fragment order bias_bf[h][nt][l16][row].
// R6: k_attn: (a) XOR-swizzled vT_l/S_l scatter (kills 4-way bank conflicts),
//     (b) precomputed gather offsets t_idx[win][kk] (no div/mod/ring in hot
//     kernel; unified kall/vall buffers so one offset serves K and V),
//     (c) invalid keys folded into bias (-1e30), pool mask via 256-entry LDS,
//     (d) XCD-aware block swizzle so 6 heads/window share L2.
// R7: identical to R6 (round 2 bench was an infra failure; resubmit).

#define DIM 192
#define HEADS 6
#define HD 32
#define WA 49
#define NKEY 230
#define SSTR 272                 // S/P row stride in shorts
#define VSTR 264                 // vT row stride in shorts
#define SCALE_F 0.17677669529663687f
#define NFINE 100352             // 8*112*112 fine tokens
#define POOLBASE (NFINE * DIM)   // element offset of pooled rows in kall/vall

typedef __attribute__((ext_vector_type(8))) short bf16x8;  // 8 bf16 in 4 VGPRs
typedef __attribute__((ext_vector_type(4))) float f32x4;

__device__ __forceinline__ short f2bf(float f) {
  union { float f; uint32_t u; } v; v.f = f;
  uint32_t u = v.u;
  return (short)((u + 0x7FFFu + ((u >> 16) & 1u)) >> 16);  // RNE
}

__device__ __forceinline__ float bf2f(short s) {
  union { uint32_t u; float f; } v;
  v.u = ((uint32_t)(uint16_t)s) << 16;
  return v.f;
}

// ---------------- setup: weights, gather-offset table, bias table ----------
__global__ __launch_bounds__(256) void k_setup(
    const float* __restrict__ qkv_w, const float* __restrict__ proj_w,
    const float* __restrict__ rpb_table, const float* __restrict__ rpb_nb,
    const float* __restrict__ rpb_win,
    short* __restrict__ w1, short* __restrict__ w1s, short* __restrict__ w2s,
    int* __restrict__ t_idx, short* __restrict__ bias_bf) {
  __shared__ int2 ring_s[132];
  if (threadIdx.x < 132) {
    int e = threadIdx.x;
    int cnt = 0, fdr = 0, fdc = 0;
    for (int idx = 0; idx < 196; ++idx) {
      int s = idx / 49, rc = idx % 49, r = rc / 7, c = rc % 7;
      bool valid;
      if (s == 0)      valid = (r >= 4) || (c >= 4);
      else if (s == 1) valid = (r >= 4) || (c < 3);
      else if (s == 2) valid = (r < 3)  || (c >= 4);
      else             valid = (r < 3)  || (c < 3);
      if (valid) {
        if (cnt == e) { fdr = r + ((s < 2) ? 3 : -3); fdc = c + (((s & 1) == 0) ? 3 : -3); }
        ++cnt;
      }
    }
    ring_s[e] = make_int2(fdr, fdc);
  }
  __syncthreads();

  const int tid = blockIdx.x * blockDim.x + threadIdx.x;
  const int nth = gridDim.x * blockDim.x;
  for (int i = tid; i < 576 * DIM; i += nth) {
    float fv = qkv_w[i];
    w1[i] = f2bf(fv);
    int r = i / DIM, c = i % DIM;
    int t = r >> 5, ntl = (r >> 4) & 1, lr = r & 15;
    int ks = c >> 5, quad = (c >> 3) & 3, e = c & 7;
    w1s[t * 6144 + (((ntl * 6 + ks) * 4 + quad) * 16 + lr) * 8 + e] = f2bf(fv);
  }
  for (int i = tid; i < DIM * DIM; i += nth) {
    int r = i / DIM, c = i % DIM;
    int t = r >> 5, ntl = (r >> 4) & 1, lr = r & 15;
    int ks = c >> 5, quad = (c >> 3) & 3, e = c & 7;
    w2s[t * 6144 + (((ntl * 6 + ks) * 4 + quad) * 16 + lr) * 8 + e] = f2bf(proj_w[i]);
  }
  // gather offsets: element offset into kall/vall (-1 = zero/invalid)
  for (int i = tid; i < 2048 * NKEY; i += nth) {
    int win = i / NKEY, kk = i - win * NKEY;
    int b = win >> 8, wr = (win >> 4) & 15, wc = win & 15;
    int off;
    if (kk < 49) {
      int ii = wr * 7 + kk / 7, jj = wc * 7 + kk % 7;
      off = ((b * 112 + ii) * 112 + jj) * DIM;
    } else if (kk < 181) {
      int2 rr = ring_s[kk - 49];
      int ii = wr * 7 + rr.x; if (ii < 0) ii += 112; if (ii >= 112) ii -= 112;
      int jj = wc * 7 + rr.y; if (jj < 0) jj += 112; if (jj >= 112) jj -= 112;
      off = ((b * 112 + ii) * 112 + jj) * DIM;
    } else {
      int p = kk - 181;
      int ii = wr - 3 + p / 7, jj = wc - 3 + p % 7;
      off = (ii >= 0 && ii < 16 && jj >= 0 && jj < 16)
              ? (POOLBASE + ((b * 16 + ii) * 16 + jj) * DIM) : -1;
    }
    t_idx[(win << 8) + kk] = off;
  }
  // bias_bf: [h][nt][l16][row64] bf16; invalid key (>=NKEY) -> -1e30
  for (int i = tid; i < HEADS * 15 * 1024; i += nth) {
    int row = i & 63, l16v = (i >> 6) & 15;
    int rem = i >> 10, nt = rem % 15, h = rem / 15;
    int kk = nt * 16 + l16v;
    float bv = 0.f;
    if (kk >= NKEY) {
      bv = -1e30f;
    } else if (row < WA) {
      if (kk < 49) {
        int ar = row / 7, ac = row % 7, br = kk / 7, bc = kk % 7;
        bv = rpb_table[((ar - br + 6) * 13 + (ac - bc + 6)) * HEADS + h];
      } else if (kk < 181) {
        bv = rpb_nb[((size_t)h * WA + row) * 132 + (kk - 49)];
      } else {
        int p = kk - 181;
        int ar = row / 7, ac = row % 7, br = p / 7, bc = p % 7;
        bv = rpb_win[h * 169 + (ar - br + 6) * 13 + (ac - bc + 6)];
      }
    }
    bias_bf[i] = f2bf(bv);
  }
}

// ---------------- QKV on fine map: M=100352, N=576, K=192 ----------------
__global__ __launch_bounds__(256, 4) void k_qkv_main(
    const float* __restrict__ x, const short* __restrict__ w1s, const float* __restrict__ qkv_b,
    short* __restrict__ qw, short* __restrict__ kn, short* __restrict__ vn) {
  __shared__ __align__(16) short wbuf[2][6144];
  const int tid = threadIdx.x;
  const int wave = tid >> 6, lane = tid & 63, quad = lane >> 4, l16 = lane & 15;
  const int mbase = blockIdx.x * 128;

  bf16x8 afr[2][6];
#pragma unroll
  for (int mt = 0; mt < 2; ++mt) {
    const float* xrow = x + (size_t)(mbase + wave * 32 + mt * 16 + l16) * DIM + quad * 8;
#pragma unroll
    for (int ks = 0; ks < 6; ++ks) {
      float4 f0 = *(const float4*)(xrow + ks * 32);
      float4 f1 = *(const float4*)(xrow + ks * 32 + 4);
      bf16x8 a;
      a[0] = f2bf(f0.x); a[1] = f2bf(f0.y); a[2] = f2bf(f0.z); a[3] = f2bf(f0.w);
      a[4] = f2bf(f1.x); a[5] = f2bf(f1.y); a[6] = f2bf(f1.z); a[7] = f2bf(f1.w);
      afr[mt][ks] = a;
    }
  }
  uint32_t q_base[2][4], kv_base[2][4];
#pragma unroll
  for (int mt = 0; mt < 2; ++mt)
#pragma unroll
    for (int rg = 0; rg < 4; ++rg) {
      int m = mbase + wave * 32 + mt * 16 + quad * 4 + rg;
      int bb = m / 12544, rem = m % 12544;
      int i = rem / 112, j = rem % 112;
      int wr = i / 7, rr = i % 7, wc = j / 7, cc = j % 7;
      int winid = (bb * 16 + wr) * 16 + wc;
      q_base[mt][rg]  = ((uint32_t)winid * WA + (rr * 7 + cc)) * DIM;
      kv_base[mt][rg] = (uint32_t)m * DIM;
    }

  int4 st[3];
  {
    const int4* src = (const int4*)w1s + tid;
#pragma unroll
    for (int it = 0; it < 3; ++it) st[it] = src[it * 256];
  }
  for (int t = 0; t < 18; ++t) {
    short* buf = wbuf[t & 1];
#pragma unroll
    for (int it = 0; it < 3; ++it) ((int4*)buf)[tid + it * 256] = st[it];
    __syncthreads();
    if (t < 17) {
      const int4* src = (const int4*)(w1s + (t + 1) * 6144) + tid;
#pragma unroll
      for (int it = 0; it < 3; ++it) st[it] = src[it * 256];
    }
#pragma unroll
    for (int ntl = 0; ntl < 2; ++ntl) {
      const int n = t * 32 + ntl * 16 + l16;
      bf16x8 bfr[6];
#pragma unroll
      for (int ks = 0; ks < 6; ++ks)
        bfr[ks] = *(const bf16x8*)&buf[(((ntl * 6 + ks) * 4 + quad) * 16 + l16) * 8];
      const float bias = qkv_b[n];
#pragma unroll
      for (int mt = 0; mt < 2; ++mt) {
        f32x4 acc = {0.f, 0.f, 0.f, 0.f};
#pragma unroll
        for (int ks = 0; ks < 6; ++ks)
          acc = __builtin_amdgcn_mfma_f32_16x16x32_bf16(afr[mt][ks], bfr[ks], acc, 0, 0, 0);
#pragma unroll
        for (int rg = 0; rg < 4; ++rg) {
          float vo = acc[rg] + bias;
          if (t < 6)       qw[q_base[mt][rg] + n]           = f2bf(vo * SCALE_F);
          else if (t < 12) kn[kv_base[mt][rg] + (n - 192)]  = f2bf(vo);
          else             vn[kv_base[mt][rg] + (n - 384)]  = f2bf(vo);
        }
      }
    }
  }
}

// ---------------- QKV on pooled map: M=2048, only k,v ----------
__global__ __launch_bounds__(256) void k_qkv_pool(
    const float* __restrict__ xp, const short* __restrict__ w1, const float* __restrict__ qkv_b,
    short* __restrict__ kp, short* __restrict__ vp) {
  const int tid = threadIdx.x;
  const int wave = tid >> 6, lane = tid & 63, quad = lane >> 4, l16 = lane & 15;
  const int mbase = (blockIdx.x * 4 + wave) * 16;

  bf16x8 afr[6];
  {
    const float* xrow = xp + (size_t)(mbase + l16) * DIM + quad * 8;
#pragma unroll
    for (int ks = 0; ks < 6; ++ks) {
      float4 f0 = *(const float4*)(xrow + ks * 32);
      float4 f1 = *(const float4*)(xrow + ks * 32 + 4);
      bf16x8 a;
      a[0] = f2bf(f0.x); a[1] = f2bf(f0.y); a[2] = f2bf(f0.z); a[3] = f2bf(f0.w);
      a[4] = f2bf(f1.x); a[5] = f2bf(f1.y); a[6] = f2bf(f1.z); a[7] = f2bf(f1.w);
      afr[ks] = a;
    }
  }
  for (int nt = 12; nt < 36; ++nt) {
    const int n = nt * 16 + l16;
    const short* wrow = w1 + (size_t)n * DIM + quad * 8;
    f32x4 acc = {0.f, 0.f, 0.f, 0.f};
#pragma unroll
    for (int ks = 0; ks < 6; ++ks)
      acc = __builtin_amdgcn_mfma_f32_16x16x32_bf16(afr[ks], *(const bf16x8*)(wrow + ks * 32), acc, 0, 0, 0);
    const float bias = qkv_b[n];
#pragma unroll
    for (int rg = 0; rg < 4; ++rg) {
      int m = mbase + quad * 4 + rg;
      float vo = acc[rg] + bias;
      if (nt < 24) kp[(size_t)m * DIM + (n - 192)] = f2bf(vo);
      else         vp[(size_t)m * DIM + (n - 384)] = f2bf(vo);
    }
  }
}

// ---------------- attention v4 (R6) ----------------
__global__ __launch_bounds__(256, 3) void k_attn(
    const short* __restrict__ qw, const short* __restrict__ kall, const short* __restrict__ vall,
    const short* __restrict__ bias_bf, const int* __restrict__ t_idx,
    short* __restrict__ ao) {
  __shared__ __align__(16) char smem[52736];
  short* vT_l  = (short*)smem;
  short* k_l   = (short*)(smem + 16896);
  short* q_l   = (short*)(smem + 16896 + 19200);
  short* S_l   = (short*)(smem + 16896);          // overlay (phase >= 3)
  float* pmask = (float*)(smem + 51712);          // 256 floats

  const int tid = threadIdx.x;
  // XCD-aware swizzle: 6 heads of a window land on the same XCD's L2.
  const int bid = ((int)blockIdx.x & 7) * 1536 + ((int)blockIdx.x >> 3);
  const int win = bid / HEADS;
  const int h   = bid - win * HEADS;
  const int wr  = (win >> 4) & 15;
  const int wc  = win & 15;
  const int wave = tid >> 6, lane = tid & 63, quad = lane >> 4, l16 = lane & 15;

  {
    int* kli = (int*)k_l;
    for (int i = tid; i < 200; i += 256) kli[4600 + i] = 0;
    int* qli = (int*)q_l;
    for (int i = tid; i < 300; i += 256) qli[980 + i] = 0;
    if (tid < 128) {
      int ch = tid >> 2, j = tid & 3;
      *(int4*)&vT_l[ch * VSTR + ((224 + j * 8) ^ (((ch >> 3) & 3) << 4))] = make_int4(0, 0, 0, 0);
    }
    // pool-boundary mask over key index space (0 for non-pool keys)
    {
      float pm = 0.f;
      if (tid >= 181 && tid < NKEY) {
        int p = tid - 181;
        int pi = wr - 3 + p / 7, pj = wc - 3 + p % 7;
        if (pi < 0 || pi >= 16 || pj < 0 || pj >= 16) pm = -100.f;
      }
      pmask[tid] = pm;
    }
  }
  __syncthreads();

  if (tid < 196) {
    int r = tid >> 2, part = tid & 3;
    *(int4*)&q_l[r * 40 + part * 8] =
        *(const int4*)(qw + ((size_t)win * WA + r) * DIM + h * HD + part * 8);
  }
  {
    const int part = tid & 3;
    const int choff = h * HD + part * 8;
    const int* tix = t_idx + (win << 8);
#pragma unroll
    for (int it = 0; it < 4; ++it) {
      int kk = it * 64 + (tid >> 2);
      if (kk < NKEY) {
        int off = tix[kk];
        int4 kvv = make_int4(0, 0, 0, 0), vvv = make_int4(0, 0, 0, 0);
        if (off >= 0) {
          kvv = *(const int4*)(kall + off + choff);
          vvv = *(const int4*)(vall + off + choff);
        }
        *(int4*)&k_l[kk * 40 + part * 8] = kvv;
        const short* vs = (const short*)&vvv;
        const int kkx = kk ^ (part << 4);   // vT scatter swizzle (ch>>3 == part)
#pragma unroll
        for (int e = 0; e < 8; ++e) vT_l[(part * 8 + e) * VSTR + kkx] = vs[e];
      }
    }
  }
  __syncthreads();

  f32x4 acc[15];
  {
    bf16x8 qfr = *(const bf16x8*)&q_l[(wave * 16 + l16) * 40 + quad * 8];
#pragma unroll
    for (int nt = 0; nt < 15; ++nt) {
      bf16x8 kfr = *(const bf16x8*)&k_l[(nt * 16 + l16) * 40 + quad * 8];
      f32x4 z = {0.f, 0.f, 0.f, 0.f};
      acc[nt] = __builtin_amdgcn_mfma_f32_16x16x32_bf16(qfr, kfr, z, 0, 0, 0);
    }
  }
  const int rowb = wave * 16 + quad * 4;
  // bias (invalid keys pre-encoded as -1e30) + pool mask from LDS
  {
    const short* bb = bias_bf + ((size_t)(h * 15 * 16 + l16)) * 64 + rowb;
#pragma unroll
    for (int nt = 0; nt < 15; ++nt) {
      int2 braw = *(const int2*)(bb + nt * 1024);
      const short* bs = (const short*)&braw;
      const float pm = pmask[nt * 16 + l16];
#pragma unroll
      for (int rg = 0; rg < 4; ++rg)
        acc[nt][rg] = acc[nt][rg] + bf2f(bs[rg]) + pm;
    }
  }
  float m4[4] = {-1e30f, -1e30f, -1e30f, -1e30f};
#pragma unroll
  for (int nt = 0; nt < 15; ++nt)
#pragma unroll
    for (int rg = 0; rg < 4; ++rg) m4[rg] = fmaxf(m4[rg], acc[nt][rg]);
#pragma unroll
  for (int msk = 1; msk <= 8; msk <<= 1)
#pragma unroll
    for (int rg = 0; rg < 4; ++rg) m4[rg] = fmaxf(m4[rg], __shfl_xor(m4[rg], msk));
  float s4[4] = {0.f, 0.f, 0.f, 0.f};
#pragma unroll
  for (int nt = 0; nt < 15; ++nt)
#pragma unroll
    for (int rg = 0; rg < 4; ++rg) {
      float e = __expf(acc[nt][rg] - m4[rg]);
      acc[nt][rg] = e; s4[rg] += e;
    }
#pragma unroll
  for (int msk = 1; msk <= 8; msk <<= 1)
#pragma unroll
    for (int rg = 0; rg < 4; ++rg) s4[rg] += __shfl_xor(s4[rg], msk);
  float inv4[4];
#pragma unroll
  for (int rg = 0; rg < 4; ++rg) inv4[rg] = 1.f / s4[rg];
#pragma unroll
  for (int nt = 0; nt < 15; ++nt)
#pragma unroll
    for (int rg = 0; rg < 4; ++rg) acc[nt][rg] *= inv4[rg];

  __syncthreads();

  // S store, swizzled: col' = col ^ (((row>>2)&3)<<4); here (row>>2)&3 == quad
#pragma unroll
  for (int nt = 0; nt < 15; ++nt)
#pragma unroll
    for (int rg = 0; rg < 4; ++rg)
      S_l[(rowb + rg) * SSTR + ((nt * 16 + l16) ^ (quad << 4))] = f2bf(acc[nt][rg]);
  {
    int rr = tid >> 2, c0 = 240 + (tid & 3) * 4;
    *(int2*)&S_l[rr * SSTR + (c0 ^ (((rr >> 2) & 3) << 4))] = make_int2(0, 0);
  }
  __syncthreads();

  const int fsr = (l16 >> 2) << 4;  // S read swizzle: (row>>2)&3 == l16>>2
#pragma unroll
  for (int nt2 = 0; nt2 < 2; ++nt2) {
    f32x4 acc2 = {0.f, 0.f, 0.f, 0.f};
    const int fvr = (((nt2 * 16 + l16) >> 3) & 3) << 4;  // vT read swizzle
#pragma unroll
    for (int k0 = 0; k0 < 8; ++k0) {
      bf16x8 pfr = *(const bf16x8*)&S_l[(wave * 16 + l16) * SSTR + ((k0 * 32 + quad * 8) ^ fsr)];
      bf16x8 vfr = *(const bf16x8*)&vT_l[(nt2 * 16 + l16) * VSTR + ((k0 * 32 + quad * 8) ^ fvr)];
      acc2 = __builtin_amdgcn_mfma_f32_16x16x32_bf16(pfr, vfr, acc2, 0, 0, 0);
    }
#pragma unroll
    for (int rg = 0; rg < 4; ++rg) {
      int row = rowb + rg;
      if (row < WA)
        ao[((size_t)win * WA + row) * DIM + h * HD + nt2 * 16 + l16] = f2bf(acc2[rg]);
    }
  }
}

// ---------------- proj: M=100352, N=192, K=192, fp32 out ----------------
__global__ __launch_bounds__(256, 4) void k_proj(
    const short* __restrict__ ao, const short* __restrict__ w2s, const float* __restrict__ pb,
    float* __restrict__ out) {
  __shared__ __align__(16) short wbuf[2][6144];
  const int tid = threadIdx.x;
  const int wave = tid >> 6, lane = tid & 63, quad = lane >> 4, l16 = lane & 15;
  const int mbase = blockIdx.x * 128;

  bf16x8 afr[2][6];
#pragma unroll
  for (int mt = 0; mt < 2; ++mt) {
    const short* arow = ao + (size_t)(mbase + wave * 32 + mt * 16 + l16) * DIM + quad * 8;
#pragma unroll
    for (int ks = 0; ks < 6; ++ks) afr[mt][ks] = *(const bf16x8*)(arow + ks * 32);
  }
  int4 st[3];
  {
    const int4* src = (const int4*)w2s + tid;
#pragma unroll
    for (int it = 0; it < 3; ++it) st[it] = src[it * 256];
  }
  for (int t = 0; t < 6; ++t) {
    short* buf = wbuf[t & 1];
#pragma unroll
    for (int it = 0; it < 3; ++it) ((int4*)buf)[tid + it * 256] = st[it];
    __syncthreads();
    if (t < 5) {
      const int4* src = (const int4*)(w2s + (t + 1) * 6144) + tid;
#pragma unroll
      for (int it = 0; it < 3; ++it) st[it] = src[it * 256];
    }
#pragma unroll
    for (int ntl = 0; ntl < 2; ++ntl) {
      const int n = t * 32 + ntl * 16 + l16;
      bf16x8 bfr[6];
#pragma unroll
      for (int ks = 0; ks < 6; ++ks)
        bfr[ks] = *(const bf16x8*)&buf[(((ntl * 6 + ks) * 4 + quad) * 16 + l16) * 8];
      const float bias = pb[n];
#pragma unroll
      for (int mt = 0; mt < 2; ++mt) {
        f32x4 acc = {0.f, 0.f, 0.f, 0.f};
#pragma unroll
        for (int ks = 0; ks < 6; ++ks)
          acc = __builtin_amdgcn_mfma_f32_16x16x32_bf16(afr[mt][ks], bfr[ks], acc, 0, 0, 0);
#pragma unroll
        for (int rg = 0; rg < 4; ++rg)
          out[(size_t)(mbase + wave * 32 + mt * 16 + quad * 4 + rg) * DIM + n] = acc[rg] + bias;
      }
    }
  }
}

extern "C" void kernel_launch(void* const* d_in, const int* in_sizes, int n_in,
                              void* d_out, int out_size, void* d_ws, size_t ws_size,
                              hipStream_t stream) {
  (void)in_sizes; (void)n_in; (void)out_size; (void)ws_size;
  const float* x         = (const float*)d_in[0];
  const float* xp        = (const float*)d_in[1];
  const float* qkv_w     = (const float*)d_in[2];
  const float* qkv_b     = (const float*)d_in[3];
  const float* proj_w    = (const float*)d_in[4];
  const float* proj_b    = (const float*)d_in[5];
  const float* rpb_table = (const float*)d_in[6];
  const float* rpb_nb    = (const float*)d_in[7];
  const float* rpb_win   = (const float*)d_in[8];

  char* ws = (char*)d_ws;
  size_t off = 0;
  auto alloc = [&](size_t bytes) -> void* {
    void* p = ws + off; off = (off + bytes + 255) & ~(size_t)255; return p;
  };
  short* w1       = (short*)alloc((size_t)576 * DIM * 2);
  short* w1s      = (short*)alloc((size_t)576 * DIM * 2);
  short* w2s      = (short*)alloc((size_t)DIM * DIM * 2);
  short* bias_bf  = (short*)alloc((size_t)HEADS * 15 * 1024 * 2);
  int*   t_idx    = (int*)  alloc((size_t)2048 * 256 * 4);
  short* qw       = (short*)alloc((size_t)2048 * WA * DIM * 2);
  short* kall     = (short*)alloc((size_t)(NFINE + 2048) * DIM * 2);
  short* vall     = (short*)alloc((size_t)(NFINE + 2048) * DIM * 2);
  short* ao       = (short*)alloc((size_t)2048 * WA * DIM * 2);

  k_setup<<<dim3(64), dim3(256), 0, stream>>>(qkv_w, proj_w, rpb_table, rpb_nb, rpb_win,
                                              w1, w1s, w2s, t_idx, bias_bf);
  k_qkv_main<<<dim3(784), dim3(256), 0, stream>>>(x, w1s, qkv_b, qw, kall, vall);
  k_qkv_pool<<<dim3(32), dim3(256), 0, stream>>>(xp, w1, qkv_b,
                                                 kall + (size_t)POOLBASE, vall + (size_t)POOLBASE);
  k_attn<<<dim3(12288), dim3(256), 0, stream>>>(qw, kall, vall, bias_bf, t_idx, ao);
  k_proj<<<dim3(784), dim3(256), 0, stream>>>(ao, w2s, proj_b, (float*)d_out);
}

// Round 4
// 474.658 us; speedup vs baseline: 1.1183x; 1.0768x over previous
//
#include <hip/hip_runtime.h>
#include <stdint.h>

// WindowAttention (focal) on gfx950.
// Pipeline: k_setup -> k_qkv_main -> k_qkv_pool -> k_attn -> k_proj
// R6: XOR-swizzled LDS, t_idx gather, bias-folded validity, XCD swizzle.
// R8: k_attn: (a) q_l removed (direct global Q-fragment load, zero reuse),
//     (b) S buffer halved (64x136) + two-pass PV -> LDS 52736->37120 B ->
//     4 blocks/CU, (c) v_cvt_pk_bf16_f32 for all bf16 packing (S, ao),
//     (d) softmax normalization deferred to PV epilogue (60 muls -> 8),
//     (e) conflict-free 1-bit S swizzle. k_qkv_main: cvt_pk epilogue
//     pairing across mt tiles.

#define DIM 192
#define HEADS 6
#define HD 32
#define WA 49
#define NKEY 230
#define VSTR 264                 // vT row stride in shorts
#define SSTR2 136                // S half-buffer row stride in shorts
#define SCALE_F 0.17677669529663687f
#define NFINE 100352             // 8*112*112 fine tokens
#define POOLBASE (NFINE * DIM)   // element offset of pooled rows in kall/vall

typedef __attribute__((ext_vector_type(8))) short bf16x8;  // 8 bf16 in 4 VGPRs
typedef __attribute__((ext_vector_type(4))) float f32x4;

__device__ __forceinline__ short f2bf(float f) {
  union { float f; uint32_t u; } v; v.f = f;
  uint32_t u = v.u;
  return (short)((u + 0x7FFFu + ((u >> 16) & 1u)) >> 16);  // RNE
}

__device__ __forceinline__ float bf2f(short s) {
  union { uint32_t u; float f; } v;
  v.u = ((uint32_t)(uint16_t)s) << 16;
  return v.f;
}

__device__ __forceinline__ uint32_t cvtpk(float lo, float hi) {
  uint32_t r;
  asm("v_cvt_pk_bf16_f32 %0, %1, %2" : "=v"(r) : "v"(lo), "v"(hi));
  return r;
}

// ---------------- setup: weights, gather-offset table, bias table ----------
__global__ __launch_bounds__(256) void k_setup(
    const float* __restrict__ qkv_w, const float* __restrict__ proj_w,
    const float* __restrict__ rpb_table, const float* __restrict__ rpb_nb,
    const float* __restrict__ rpb_win,
    short* __restrict__ w1, short* __restrict__ w1s, short* __restrict__ w2s,
    int* __restrict__ t_idx, short* __restrict__ bias_bf) {
  __shared__ int2 ring_s[132];
  if (threadIdx.x < 132) {
    int e = threadIdx.x;
    int cnt = 0, fdr = 0, fdc = 0;
    for (int idx = 0; idx < 196; ++idx) {
      int s = idx / 49, rc = idx % 49, r = rc / 7, c = rc % 7;
      bool valid;
      if (s == 0)      valid = (r >= 4) || (c >= 4);
      else if (s == 1) valid = (r >= 4) || (c < 3);
      else if (s == 2) valid = (r < 3)  || (c >= 4);
      else             valid = (r < 3)  || (c < 3);
      if (valid) {
        if (cnt == e) { fdr = r + ((s < 2) ? 3 : -3); fdc = c + (((s & 1) == 0) ? 3 : -3); }
        ++cnt;
      }
    }
    ring_s[e] = make_int2(fdr, fdc);
  }
  __syncthreads();

  const int tid = blockIdx.x * blockDim.x + threadIdx.x;
  const int nth = gridDim.x * blockDim.x;
  for (int i = tid; i < 576 * DIM; i += nth) {
    float fv = qkv_w[i];
    w1[i] = f2bf(fv);
    int r = i / DIM, c = i % DIM;
    int t = r >> 5, ntl = (r >> 4) & 1, lr = r & 15;
    int ks = c >> 5, quad = (c >> 3) & 3, e = c & 7;
    w1s[t * 6144 + (((ntl * 6 + ks) * 4 + quad) * 16 + lr) * 8 + e] = f2bf(fv);
  }
  for (int i = tid; i < DIM * DIM; i += nth) {
    int r = i / DIM, c = i % DIM;
    int t = r >> 5, ntl = (r >> 4) & 1, lr = r & 15;
    int ks = c >> 5, quad = (c >> 3) & 3, e = c & 7;
    w2s[t * 6144 + (((ntl * 6 + ks) * 4 + quad) * 16 + lr) * 8 + e] = f2bf(proj_w[i]);
  }
  // gather offsets: element offset into kall/vall (-1 = zero/invalid)
  for (int i = tid; i < 2048 * NKEY; i += nth) {
    int win = i / NKEY, kk = i - win * NKEY;
    int b = win >> 8, wr = (win >> 4) & 15, wc = win & 15;
    int off;
    if (kk < 49) {
      int ii = wr * 7 + kk / 7, jj = wc * 7 + kk % 7;
      off = ((b * 112 + ii) * 112 + jj) * DIM;
    } else if (kk < 181) {
      int2 rr = ring_s[kk - 49];
      int ii = wr * 7 + rr.x; if (ii < 0) ii += 112; if (ii >= 112) ii -= 112;
      int jj = wc * 7 + rr.y; if (jj < 0) jj += 112; if (jj >= 112) jj -= 112;
      off = ((b * 112 + ii) * 112 + jj) * DIM;
    } else {
      int p = kk - 181;
      int ii = wr - 3 + p / 7, jj = wc - 3 + p % 7;
      off = (ii >= 0 && ii < 16 && jj >= 0 && jj < 16)
              ? (POOLBASE + ((b * 16 + ii) * 16 + jj) * DIM) : -1;
    }
    t_idx[(win << 8) + kk] = off;
  }
  // bias_bf: [h][nt][l16][row64] bf16; invalid key (>=NKEY) -> -1e30
  for (int i = tid; i < HEADS * 15 * 1024; i += nth) {
    int row = i & 63, l16v = (i >> 6) & 15;
    int rem = i >> 10, nt = rem % 15, h = rem / 15;
    int kk = nt * 16 + l16v;
    float bv = 0.f;
    if (kk >= NKEY) {
      bv = -1e30f;
    } else if (row < WA) {
      if (kk < 49) {
        int ar = row / 7, ac = row % 7, br = kk / 7, bc = kk % 7;
        bv = rpb_table[((ar - br + 6) * 13 + (ac - bc + 6)) * HEADS + h];
      } else if (kk < 181) {
        bv = rpb_nb[((size_t)h * WA + row) * 132 + (kk - 49)];
      } else {
        int p = kk - 181;
        int ar = row / 7, ac = row % 7, br = p / 7, bc = p % 7;
        bv = rpb_win[h * 169 + (ar - br + 6) * 13 + (ac - bc + 6)];
      }
    }
    bias_bf[i] = f2bf(bv);
  }
}

// ---------------- QKV on fine map: M=100352, N=576, K=192 ----------------
__global__ __launch_bounds__(256, 4) void k_qkv_main(
    const float* __restrict__ x, const short* __restrict__ w1s, const float* __restrict__ qkv_b,
    short* __restrict__ qw, short* __restrict__ kn, short* __restrict__ vn) {
  __shared__ __align__(16) short wbuf[2][6144];
  const int tid = threadIdx.x;
  const int wave = tid >> 6, lane = tid & 63, quad = lane >> 4, l16 = lane & 15;
  const int mbase = blockIdx.x * 128;

  bf16x8 afr[2][6];
#pragma unroll
  for (int mt = 0; mt < 2; ++mt) {
    const float* xrow = x + (size_t)(mbase + wave * 32 + mt * 16 + l16) * DIM + quad * 8;
#pragma unroll
    for (int ks = 0; ks < 6; ++ks) {
      float4 f0 = *(const float4*)(xrow + ks * 32);
      float4 f1 = *(const float4*)(xrow + ks * 32 + 4);
      bf16x8 a;
      a[0] = f2bf(f0.x); a[1] = f2bf(f0.y); a[2] = f2bf(f0.z); a[3] = f2bf(f0.w);
      a[4] = f2bf(f1.x); a[5] = f2bf(f1.y); a[6] = f2bf(f1.z); a[7] = f2bf(f1.w);
      afr[mt][ks] = a;
    }
  }
  uint32_t q_base[2][4], kv_base[2][4];
#pragma unroll
  for (int mt = 0; mt < 2; ++mt)
#pragma unroll
    for (int rg = 0; rg < 4; ++rg) {
      int m = mbase + wave * 32 + mt * 16 + quad * 4 + rg;
      int bb = m / 12544, rem = m % 12544;
      int i = rem / 112, j = rem % 112;
      int wr = i / 7, rr = i % 7, wc = j / 7, cc = j % 7;
      int winid = (bb * 16 + wr) * 16 + wc;
      q_base[mt][rg]  = ((uint32_t)winid * WA + (rr * 7 + cc)) * DIM;
      kv_base[mt][rg] = (uint32_t)m * DIM;
    }

  int4 st[3];
  {
    const int4* src = (const int4*)w1s + tid;
#pragma unroll
    for (int it = 0; it < 3; ++it) st[it] = src[it * 256];
  }
  for (int t = 0; t < 18; ++t) {
    short* buf = wbuf[t & 1];
#pragma unroll
    for (int it = 0; it < 3; ++it) ((int4*)buf)[tid + it * 256] = st[it];
    __syncthreads();
    if (t < 17) {
      const int4* src = (const int4*)(w1s + (t + 1) * 6144) + tid;
#pragma unroll
      for (int it = 0; it < 3; ++it) st[it] = src[it * 256];
    }
#pragma unroll
    for (int ntl = 0; ntl < 2; ++ntl) {
      const int n = t * 32 + ntl * 16 + l16;
      bf16x8 bfr[6];
#pragma unroll
      for (int ks = 0; ks < 6; ++ks)
        bfr[ks] = *(const bf16x8*)&buf[(((ntl * 6 + ks) * 4 + quad) * 16 + l16) * 8];
      const float bias = qkv_b[n];
      f32x4 ac[2];
#pragma unroll
      for (int mt = 0; mt < 2; ++mt) {
        f32x4 a = {0.f, 0.f, 0.f, 0.f};
#pragma unroll
        for (int ks = 0; ks < 6; ++ks)
          a = __builtin_amdgcn_mfma_f32_16x16x32_bf16(afr[mt][ks], bfr[ks], a, 0, 0, 0);
        ac[mt] = a;
      }
      if (t < 6) {
        const float bq = bias * SCALE_F;
#pragma unroll
        for (int rg = 0; rg < 4; ++rg) {
          uint32_t r = cvtpk(fmaf(ac[0][rg], SCALE_F, bq), fmaf(ac[1][rg], SCALE_F, bq));
          qw[q_base[0][rg] + n] = (short)r;
          qw[q_base[1][rg] + n] = (short)(r >> 16);
        }
      } else if (t < 12) {
#pragma unroll
        for (int rg = 0; rg < 4; ++rg) {
          uint32_t r = cvtpk(ac[0][rg] + bias, ac[1][rg] + bias);
          kn[kv_base[0][rg] + (n - 192)] = (short)r;
          kn[kv_base[1][rg] + (n - 192)] = (short)(r >> 16);
        }
      } else {
#pragma unroll
        for (int rg = 0; rg < 4; ++rg) {
          uint32_t r = cvtpk(ac[0][rg] + bias, ac[1][rg] + bias);
          vn[kv_base[0][rg] + (n - 384)] = (short)r;
          vn[kv_base[1][rg] + (n - 384)] = (short)(r >> 16);
        }
      }
    }
  }
}

// ---------------- QKV on pooled map: M=2048, only k,v ----------
__global__ __launch_bounds__(256) void k_qkv_pool(
    const float* __restrict__ xp, const short* __restrict__ w1, const float* __restrict__ qkv_b,
    short* __restrict__ kp, short* __restrict__ vp) {
  const int tid = threadIdx.x;
  const int wave = tid >> 6, lane = tid & 63, quad = lane >> 4, l16 = lane & 15;
  const int mbase = (blockIdx.x * 4 + wave) * 16;

  bf16x8 afr[6];
  {
    const float* xrow = xp + (size_t)(mbase + l16) * DIM + quad * 8;
#pragma unroll
    for (int ks = 0; ks < 6; ++ks) {
      float4 f0 = *(const float4*)(xrow + ks * 32);
      float4 f1 = *(const float4*)(xrow + ks * 32 + 4);
      bf16x8 a;
      a[0] = f2bf(f0.x); a[1] = f2bf(f0.y); a[2] = f2bf(f0.z); a[3] = f2bf(f0.w);
      a[4] = f2bf(f1.x); a[5] = f2bf(f1.y); a[6] = f2bf(f1.z); a[7] = f2bf(f1.w);
      afr[ks] = a;
    }
  }
  for (int nt = 12; nt < 36; ++nt) {
    const int n = nt * 16 + l16;
    const short* wrow = w1 + (size_t)n * DIM + quad * 8;
    f32x4 acc = {0.f, 0.f, 0.f, 0.f};
#pragma unroll
    for (int ks = 0; ks < 6; ++ks)
      acc = __builtin_amdgcn_mfma_f32_16x16x32_bf16(afr[ks], *(const bf16x8*)(wrow + ks * 32), acc, 0, 0, 0);
    const float bias = qkv_b[n];
#pragma unroll
    for (int rg = 0; rg < 4; ++rg) {
      int m = mbase + quad * 4 + rg;
      float vo = acc[rg] + bias;
      if (nt < 24) kp[(size_t)m * DIM + (n - 192)] = f2bf(vo);
      else         vp[(size_t)m * DIM + (n - 384)] = f2bf(vo);
    }
  }
}

// ---------------- attention v5 (R8): 37.1KB LDS, 4 blocks/CU ----------------
__global__ __launch_bounds__(256, 4) void k_attn(
    const short* __restrict__ qw, const short* __restrict__ kall, const short* __restrict__ vall,
    const short* __restrict__ bias_bf, const int* __restrict__ t_idx,
    short* __restrict__ ao) {
  __shared__ __align__(16) char smem[37120];
  short* vT_l  = (short*)smem;                    // 32 ch x VSTR -> 16896 B
  short* k_l   = (short*)(smem + 16896);          // 240 x 40 -> 19200 B (phase 1)
  short* S_l   = (short*)(smem + 16896);          // 64 x 136 -> 17408 B (overlay)
  float* pmask = (float*)(smem + 36096);          // 256 floats

  const int tid = threadIdx.x;
  // XCD-aware swizzle: 6 heads of a window land on the same XCD's L2.
  const int bid = ((int)blockIdx.x & 7) * 1536 + ((int)blockIdx.x >> 3);
  const int win = bid / HEADS;
  const int h   = bid - win * HEADS;
  const int wr  = (win >> 4) & 15;
  const int wc  = win & 15;
  const int wave = tid >> 6, lane = tid & 63, quad = lane >> 4, l16 = lane & 15;

  {
    int* kli = (int*)k_l;
    for (int i = tid; i < 200; i += 256) kli[4600 + i] = 0;
    if (tid < 128) {
      int ch = tid >> 2, j = tid & 3;
      *(int4*)&vT_l[ch * VSTR + ((224 + j * 8) ^ (((ch >> 3) & 3) << 4))] = make_int4(0, 0, 0, 0);
    }
    float pm = 0.f;
    if (tid >= 181 && tid < NKEY) {
      int p = tid - 181;
      int pi = wr - 3 + p / 7, pj = wc - 3 + p % 7;
      if (pi < 0 || pi >= 16 || pj < 0 || pj >= 16) pm = -100.f;
    }
    pmask[tid] = pm;
  }
  // Q fragment: direct global load, no LDS staging (zero cross-wave reuse)
  bf16x8 qfr = {0, 0, 0, 0, 0, 0, 0, 0};
  {
    const int qrow = wave * 16 + l16;
    if (qrow < WA)
      qfr = *(const bf16x8*)(qw + ((size_t)win * WA + qrow) * DIM + h * HD + quad * 8);
  }
  __syncthreads();

  {
    const int part = tid & 3;
    const int choff = h * HD + part * 8;
    const int* tix = t_idx + (win << 8);
#pragma unroll
    for (int it = 0; it < 4; ++it) {
      int kk = it * 64 + (tid >> 2);
      if (kk < NKEY) {
        int off = tix[kk];
        int4 kvv = make_int4(0, 0, 0, 0), vvv = make_int4(0, 0, 0, 0);
        if (off >= 0) {
          kvv = *(const int4*)(kall + off + choff);
          vvv = *(const int4*)(vall + off + choff);
        }
        *(int4*)&k_l[kk * 40 + part * 8] = kvv;
        const short* vs = (const short*)&vvv;
        const int kkx = kk ^ (part << 4);   // vT scatter swizzle (ch>>3 == part)
#pragma unroll
        for (int e = 0; e < 8; ++e) vT_l[(part * 8 + e) * VSTR + kkx] = vs[e];
      }
    }
  }
  __syncthreads();

  f32x4 acc[15];
#pragma unroll
  for (int nt = 0; nt < 15; ++nt) {
    bf16x8 kfr = *(const bf16x8*)&k_l[(nt * 16 + l16) * 40 + quad * 8];
    f32x4 z = {0.f, 0.f, 0.f, 0.f};
    acc[nt] = __builtin_amdgcn_mfma_f32_16x16x32_bf16(qfr, kfr, z, 0, 0, 0);
  }
  const int rowb = wave * 16 + quad * 4;
  // bias (invalid keys pre-encoded as -1e30) + pool mask from LDS
  {
    const short* bb = bias_bf + ((size_t)(h * 15 * 16 + l16)) * 64 + rowb;
#pragma unroll
    for (int nt = 0; nt < 15; ++nt) {
      int2 braw = *(const int2*)(bb + nt * 1024);
      const short* bs = (const short*)&braw;
      const float pm = pmask[nt * 16 + l16];
#pragma unroll
      for (int rg = 0; rg < 4; ++rg)
        acc[nt][rg] = acc[nt][rg] + bf2f(bs[rg]) + pm;
    }
  }
  float m4[4] = {-1e30f, -1e30f, -1e30f, -1e30f};
#pragma unroll
  for (int nt = 0; nt < 15; ++nt)
#pragma unroll
    for (int rg = 0; rg < 4; ++rg) m4[rg] = fmaxf(m4[rg], acc[nt][rg]);
#pragma unroll
  for (int msk = 1; msk <= 8; msk <<= 1)
#pragma unroll
    for (int rg = 0; rg < 4; ++rg) m4[rg] = fmaxf(m4[rg], __shfl_xor(m4[rg], msk));
  float s4[4] = {0.f, 0.f, 0.f, 0.f};
#pragma unroll
  for (int nt = 0; nt < 15; ++nt)
#pragma unroll
    for (int rg = 0; rg < 4; ++rg) {
      float e = __expf(acc[nt][rg] - m4[rg]);
      acc[nt][rg] = e; s4[rg] += e;
    }
#pragma unroll
  for (int msk = 1; msk <= 8; msk <<= 1)
#pragma unroll
    for (int rg = 0; rg < 4; ++rg) s4[rg] += __shfl_xor(s4[rg], msk);
  float inv4[4];
#pragma unroll
  for (int rg = 0; rg < 4; ++rg) inv4[rg] = 1.f / s4[rg];
  // normalization deferred to PV epilogue (acc holds unnormalized probs)

  __syncthreads();   // all waves done reading k_l before S overlay

  // ---- S half-1 (keys 0..127), conflict-free swizzle col^=((row>>3)&1)<<4 ----
  const int swS = ((quad >> 1) & 1) << 4;   // row bit3 == quad>=2
#pragma unroll
  for (int rg = 0; rg < 4; ++rg) {
    const int base = (rowb + rg) * SSTR2;
#pragma unroll
    for (int p = 0; p < 4; ++p) {
      uint32_t r = cvtpk(acc[2 * p][rg], acc[2 * p + 1][rg]);
      S_l[base + ((p * 32 + l16) ^ swS)]      = (short)r;
      S_l[base + ((p * 32 + 16 + l16) ^ swS)] = (short)(r >> 16);
    }
  }
  __syncthreads();

  const int swR = ((l16 >> 3) & 1) << 4;
  f32x4 acc2[2] = {{0.f, 0.f, 0.f, 0.f}, {0.f, 0.f, 0.f, 0.f}};
#pragma unroll
  for (int nt2 = 0; nt2 < 2; ++nt2) {
    const int fvr = (((nt2 * 16 + l16) >> 3) & 3) << 4;
#pragma unroll
    for (int k0 = 0; k0 < 4; ++k0) {
      bf16x8 pfr = *(const bf16x8*)&S_l[(wave * 16 + l16) * SSTR2 + ((k0 * 32 + quad * 8) ^ swR)];
      bf16x8 vfr = *(const bf16x8*)&vT_l[(nt2 * 16 + l16) * VSTR + ((k0 * 32 + quad * 8) ^ fvr)];
      acc2[nt2] = __builtin_amdgcn_mfma_f32_16x16x32_bf16(pfr, vfr, acc2[nt2], 0, 0, 0);
    }
  }
  __syncthreads();

  // ---- S half-2 (keys 128..239 + zero pad 240..255) ----
#pragma unroll
  for (int rg = 0; rg < 4; ++rg) {
    const int base = (rowb + rg) * SSTR2;
#pragma unroll
    for (int p = 0; p < 3; ++p) {
      uint32_t r = cvtpk(acc[8 + 2 * p][rg], acc[9 + 2 * p][rg]);
      S_l[base + ((p * 32 + l16) ^ swS)]      = (short)r;
      S_l[base + ((p * 32 + 16 + l16) ^ swS)] = (short)(r >> 16);
    }
    uint32_t r = cvtpk(acc[14][rg], 0.f);   // nt14 + zero pad (keys 240-255)
    S_l[base + ((96 + l16) ^ swS)]  = (short)r;
    S_l[base + ((112 + l16) ^ swS)] = (short)(r >> 16);
  }
  __syncthreads();

#pragma unroll
  for (int nt2 = 0; nt2 < 2; ++nt2) {
    const int fvr = (((nt2 * 16 + l16) >> 3) & 3) << 4;
#pragma unroll
    for (int k0 = 0; k0 < 4; ++k0) {
      bf16x8 pfr = *(const bf16x8*)&S_l[(wave * 16 + l16) * SSTR2 + ((k0 * 32 + quad * 8) ^ swR)];
      bf16x8 vfr = *(const bf16x8*)&vT_l[(nt2 * 16 + l16) * VSTR + ((128 + k0 * 32 + quad * 8) ^ fvr)];
      acc2[nt2] = __builtin_amdgcn_mfma_f32_16x16x32_bf16(pfr, vfr, acc2[nt2], 0, 0, 0);
    }
  }

#pragma unroll
  for (int rg = 0; rg < 4; ++rg) {
    const int row = rowb + rg;
    if (row < WA) {
      uint32_t r = cvtpk(acc2[0][rg] * inv4[rg], acc2[1][rg] * inv4[rg]);
      short* dst = ao + ((size_t)win * WA + row) * DIM + h * HD + l16;
      dst[0]  = (short)r;
      dst[16] = (short)(r >> 16);
    }
  }
}

// ---------------- proj: M=100352, N=192, K=192, fp32 out ----------------
__global__ __launch_bounds__(256, 4) void k_proj(
    const short* __restrict__ ao, const short* __restrict__ w2s, const float* __restrict__ pb,
    float* __restrict__ out) {
  __shared__ __align__(16) short wbuf[2][6144];
  const int tid = threadIdx.x;
  const int wave = tid >> 6, lane = tid & 63, quad = lane >> 4, l16 = lane & 15;
  const int mbase = blockIdx.x * 128;

  bf16x8 afr[2][6];
#pragma unroll
  for (int mt = 0; mt < 2; ++mt) {
    const short* arow = ao + (size_t)(mbase + wave * 32 + mt * 16 + l16) * DIM + quad * 8;
#pragma unroll
    for (int ks = 0; ks < 6; ++ks) afr[mt][ks] = *(const bf16x8*)(arow + ks * 32);
  }
  int4 st[3];
  {
    const int4* src = (const int4*)w2s + tid;
#pragma unroll
    for (int it = 0; it < 3; ++it) st[it] = src[it * 256];
  }
  for (int t = 0; t < 6; ++t) {
    short* buf = wbuf[t & 1];
#pragma unroll
    for (int it = 0; it < 3; ++it) ((int4*)buf)[tid + it * 256] = st[it];
    __syncthreads();
    if (t < 5) {
      const int4* src = (const int4*)(w2s + (t + 1) * 6144) + tid;
#pragma unroll
      for (int it = 0; it < 3; ++it) st[it] = src[it * 256];
    }
#pragma unroll
    for (int ntl = 0; ntl < 2; ++ntl) {
      const int n = t * 32 + ntl * 16 + l16;
      bf16x8 bfr[6];
#pragma unroll
      for (int ks = 0; ks < 6; ++ks)
        bfr[ks] = *(const bf16x8*)&buf[(((ntl * 6 + ks) * 4 + quad) * 16 + l16) * 8];
      const float bias = pb[n];
#pragma unroll
      for (int mt = 0; mt < 2; ++mt) {
        f32x4 acc = {0.f, 0.f, 0.f, 0.f};
#pragma unroll
        for (int ks = 0; ks < 6; ++ks)
          acc = __builtin_amdgcn_mfma_f32_16x16x32_bf16(afr[mt][ks], bfr[ks], acc, 0, 0, 0);
#pragma unroll
        for (int rg = 0; rg < 4; ++rg)
          out[(size_t)(mbase + wave * 32 + mt * 16 + quad * 4 + rg) * DIM + n] = acc[rg] + bias;
      }
    }
  }
}

extern "C" void kernel_launch(void* const* d_in, const int* in_sizes, int n_in,
                              void* d_out, int out_size, void* d_ws, size_t ws_size,
                              hipStream_t stream) {
  (void)in_sizes; (void)n_in; (void)out_size; (void)ws_size;
  const float* x         = (const float*)d_in[0];
  const float* xp        = (const float*)d_in[1];
  const float* qkv_w     = (const float*)d_in[2];
  const float* qkv_b     = (const float*)d_in[3];
  const float* proj_w    = (const float*)d_in[4];
  const float* proj_b    = (const float*)d_in[5];
  const float* rpb_table = (const float*)d_in[6];
  const float* rpb_nb    = (const float*)d_in[7];
  const float* rpb_win   = (const float*)d_in[8];

  char* ws = (char*)d_ws;
  size_t off = 0;
  auto alloc = [&](size_t bytes) -> void* {
    void* p = ws + off; off = (off + bytes + 255) & ~(size_t)255; return p;
  };
  short* w1       = (short*)alloc((size_t)576 * DIM * 2);
  short* w1s      = (short*)alloc((size_t)576 * DIM * 2);
  short* w2s      = (short*)alloc((size_t)DIM * DIM * 2);
  short* bias_bf  = (short*)alloc((size_t)HEADS * 15 * 1024 * 2);
  int*   t_idx    = (int*)  alloc((size_t)2048 * 256 * 4);
  short* qw       = (short*)alloc((size_t)2048 * WA * DIM * 2);
  short* kall     = (short*)alloc((size_t)(NFINE + 2048) * DIM * 2);
  short* vall     = (short*)alloc((size_t)(NFINE + 2048) * DIM * 2);
  short* ao       = (short*)alloc((size_t)2048 * WA * DIM * 2);

  k_setup<<<dim3(64), dim3(256), 0, stream>>>(qkv_w, proj_w, rpb_table, rpb_nb, rpb_win,
                                              w1, w1s, w2s, t_idx, bias_bf);
  k_qkv_main<<<dim3(784), dim3(256), 0, stream>>>(x, w1s, qkv_b, qw, kall, vall);
  k_qkv_pool<<<dim3(32), dim3(256), 0, stream>>>(xp, w1, qkv_b,
                                                 kall + (size_t)POOLBASE, vall + (size_t)POOLBASE);
  k_attn<<<dim3(12288), dim3(256), 0, stream>>>(qw, kall, vall, bias_bf, t_idx, ao);
  k_proj<<<dim3(784), dim3(256), 0, stream>>>(ao, w2s, proj_b, (float*)d_out);
}